// Round 14
// baseline (254.198 us; speedup 1.0000x reference)
//
#include <hip/hip_runtime.h>
#include <math.h>

// ---------------------------------------------------------------------------
// TemporalGuidedModule round 14 = r12 structure + barrier-free direct-load GEMM.
// Key insight: X-tile has ZERO intra-block reuse (each row/K-chunk consumed by
// exactly one wave once) -> LDS staging + per-K-step barriers were pure
// overhead. gemm3_k loads A/W fragments directly global->VGPR (W is L2-hot,
// 128KB), no barriers in the K-loop -> compiler software-pipelines freely.
// LDS only for the output-coalescing bounce. Fused r13 tail reverted.
// ---------------------------------------------------------------------------

#define PIX 16384
#define BATCH 2
#define CH 256

typedef short bf16x8 __attribute__((ext_vector_type(8)));
typedef float f32x4 __attribute__((ext_vector_type(4)));

__device__ __forceinline__ ushort f2bf(float f) {
  union { float f; unsigned u; } v; v.f = f;
  unsigned u = v.u;
  unsigned r = u + 0x7fffu + ((u >> 16) & 1u);   // RNE
  return (ushort)(r >> 16);
}
__device__ __forceinline__ float bfl(unsigned u) {
  union { unsigned u; float f; } v; v.u = u << 16; return v.f;
}
__device__ __forceinline__ float bfh(unsigned u) {
  union { unsigned u; float f; } v; v.u = u & 0xffff0000u; return v.f;
}
__device__ __forceinline__ unsigned fuse_u32(unsigned a, unsigned b, bool mul) {
  float rl = mul ? bfl(a) * bfl(b) : bfl(a) + bfl(b);
  float rh = mul ? bfh(a) * bfh(b) : bfh(a) + bfh(b);
  return (unsigned)f2bf(rl) | ((unsigned)f2bf(rh) << 16);
}

// --------------------------------------------------------------------------
// prep_k: merged tconv(x2 tensors) + weight-prep + Wv-composite (r12 verbatim).
// --------------------------------------------------------------------------
__global__ __launch_bounds__(256) void prep_k(
    const float* __restrict__ xt, const float* __restrict__ xt_1,
    ushort* __restrict__ s0, ushort* __restrict__ s1,
    const float* __restrict__ W_in1, const float* __restrict__ Wo,
    const float* __restrict__ Wt1, const float* __restrict__ Wt2,
    const float* __restrict__ Wout, const float* __restrict__ Ws,
    const float* __restrict__ Wa, const float* __restrict__ bs_off,
    const float* __restrict__ ba, ushort* __restrict__ wb,
    float* __restrict__ bsa,
    const float* __restrict__ Wv, const float* __restrict__ W_in2,
    const float* __restrict__ b_in2, const float* __restrict__ bv,
    ushort* __restrict__ wvp, float* __restrict__ bvp)
{
  __shared__ float lds[32][33];
  const int bid = blockIdx.x;
  const int tid = threadIdx.x;

  if (bid < 16384) {
    const int z = bid >> 12;
    const int rem = bid & 4095;
    const int pblk = rem & 511, cblk = rem >> 9;
    const int b = z & 1;
    const float* in = (z < 2) ? xt : xt_1;
    ushort* out = (z < 2) ? s0 : s1;
    const int p0 = pblk * 32, c0 = cblk * 32;
    const int tx = tid & 31, ty = tid >> 5;
    const float* inb = in + (size_t)b * CH * PIX;
    #pragma unroll
    for (int i = 0; i < 4; ++i)
      lds[ty + i * 8][tx] = inb[(size_t)(c0 + ty + i * 8) * PIX + p0 + tx];
    __syncthreads();
    const int cx = (tid & 15) * 2, py = tid >> 4;
    ushort* outb = out + (size_t)b * PIX * CH;
    #pragma unroll
    for (int i = 0; i < 2; ++i) {
      int pl = py + i * 16;
      unsigned lo = f2bf(lds[cx][pl]);
      unsigned hi = f2bf(lds[cx + 1][pl]);
      *(unsigned*)(outb + (size_t)(p0 + pl) * CH + c0 + cx) = lo | (hi << 16);
    }
  } else if (bid < 16384 + 1473) {
    const int blk = bid - 16384;
    const int k = tid;
    if (blk >= 1472) {
      if (k < 128) bsa[k] = bs_off[k];
      else if (k < 192) bsa[k] = ba[k - 128];
      return;
    }
    const float* src;
    if (blk < 256) src = W_in1 + (size_t)blk * 256;
    else if (blk < 512) src = Wo + (size_t)(blk - 256) * 256;
    else if (blk < 768) src = Wt1 + (size_t)(blk - 512) * 256;
    else if (blk < 1024) src = Wt2 + (size_t)(blk - 768) * 256;
    else if (blk < 1280) src = Wout + (size_t)(blk - 1024) * 256;
    else if (blk < 1408) src = Ws + (size_t)(blk - 1280) * 256;
    else src = Wa + (size_t)(blk - 1408) * 256;
    wb[(size_t)blk * 256 + k] = f2bf(src[k]);
  } else {
    const int oo = bid - 17857;
    const int k = tid;
    float acc = 0.f;
    #pragma unroll 8
    for (int c = 0; c < 256; ++c)
      acc += Wv[(size_t)oo * 256 + c] * W_in2[(size_t)c * 256 + k];
    wvp[(size_t)oo * 256 + k] = f2bf(acc);
    float* red = &lds[0][0];
    red[k] = Wv[(size_t)oo * 256 + k] * b_in2[k];
    __syncthreads();
    for (int s = 128; s > 0; s >>= 1) {
      if (k < s) red[k] += red[k + s];
      __syncthreads();
    }
    if (k == 0) bvp[oo] = red[0] + bv[oo];
  }
}

// --------------------------------------------------------------------------
// gemm3_k: barrier-free direct-load MFMA GEMM.
// Tile 128p x 64o, 4 waves (wave = 32p x 64o), 8 K-steps of 32.
// A-frag: lane(lr,g4) reads in[(p0+wv*32+fm*16+lr)*CH + t*32 + g4*8] (16B).
// W-frag: lane reads Wb[(o0+fn*16+lr)*CH + t*32 + g4*8] (L2-hot, 128KB).
// FUSE in registers (each element consumed exactly once -> same rounding).
// No LDS / no barriers in the K-loop. LDS only for output bounce.
// OMODE 0: pm bf16 out (ldo); 1: cm f32 out (transposed bounce).
// --------------------------------------------------------------------------
template<int FUSE, bool RELU, int OMODE>
__global__ __launch_bounds__(256) void gemm3_k(
    const ushort* __restrict__ in, const ushort* __restrict__ in2,
    const ushort* __restrict__ Wb, const float* __restrict__ bias,
    void* __restrict__ out, int ldo, size_t obstride)
{
  constexpr int SMEMSZ = (OMODE == 0) ? 18432 : 34816;
  __shared__ __align__(16) char smem[SMEMSZ];
  const int tid = threadIdx.x;
  const int b = blockIdx.z;
  const int p0 = blockIdx.x * 128;
  const int o0 = blockIdx.y * 64;

  const int l = tid & 63, wv = tid >> 6;
  const int lr = l & 15, g4 = l >> 4;

  const ushort* arow = in + (size_t)b * PIX * CH + (size_t)(p0 + wv * 32 + lr) * CH + g4 * 8;
  const ushort* a2row = (FUSE != 0)
      ? in2 + (size_t)b * PIX * CH + (size_t)(p0 + wv * 32 + lr) * CH + g4 * 8
      : (const ushort*)nullptr;
  const ushort* wrow = Wb + (size_t)(o0 + lr) * CH + g4 * 8;

  f32x4 acc[2][4];
  #pragma unroll
  for (int i = 0; i < 2; ++i)
    #pragma unroll
    for (int j = 0; j < 4; ++j) acc[i][j] = (f32x4){0.f, 0.f, 0.f, 0.f};

  #pragma unroll
  for (int t = 0; t < 8; ++t) {
    bf16x8 af[2], bfr[4];
    #pragma unroll
    for (int fm = 0; fm < 2; ++fm) {
      bf16x8 a = *(const bf16x8*)(arow + (size_t)fm * 16 * CH + t * 32);
      if (FUSE != 0) {
        bf16x8 a2 = *(const bf16x8*)(a2row + (size_t)fm * 16 * CH + t * 32);
        unsigned rr[4];
        const unsigned* u1 = (const unsigned*)&a;
        const unsigned* u2 = (const unsigned*)&a2;
        #pragma unroll
        for (int q = 0; q < 4; ++q) rr[q] = fuse_u32(u1[q], u2[q], FUSE == 1);
        af[fm] = *(bf16x8*)&rr[0];
      } else {
        af[fm] = a;
      }
    }
    #pragma unroll
    for (int fn = 0; fn < 4; ++fn)
      bfr[fn] = *(const bf16x8*)(wrow + (size_t)fn * 16 * CH + t * 32);
    #pragma unroll
    for (int fm = 0; fm < 2; ++fm)
      #pragma unroll
      for (int fn = 0; fn < 4; ++fn)
        acc[fm][fn] = __builtin_amdgcn_mfma_f32_16x16x32_bf16(af[fm], bfr[fn], acc[fm][fn], 0, 0, 0);
  }

  // ---- epilogue ---- C/D: col(o) = lr, row(p) = g4*4 + reg
  float bvv[4];
  #pragma unroll
  for (int fn = 0; fn < 4; ++fn) bvv[fn] = bias[o0 + fn * 16 + lr];

  if (OMODE == 1) {               // cm f32 via TRANSPOSED bounce El2[64][132] f32
    float* El2 = (float*)smem;
    #pragma unroll
    for (int fm = 0; fm < 2; ++fm)
      #pragma unroll
      for (int fn = 0; fn < 4; ++fn) {
        float4 v;
        v.x = acc[fm][fn][0] + bvv[fn]; v.y = acc[fm][fn][1] + bvv[fn];
        v.z = acc[fm][fn][2] + bvv[fn]; v.w = acc[fm][fn][3] + bvv[fn];
        if (RELU) {
          v.x = fmaxf(v.x, 0.f); v.y = fmaxf(v.y, 0.f);
          v.z = fmaxf(v.z, 0.f); v.w = fmaxf(v.w, 0.f);
        }
        *(float4*)&El2[(size_t)(fn * 16 + lr) * 132 + wv * 32 + fm * 16 + g4 * 4] = v;
      }
    __syncthreads();
    float* outb = (float*)out + (size_t)b * obstride;
    const int og = tid >> 5, seg = tid & 31;
    #pragma unroll
    for (int r = 0; r < 8; ++r) {
      const int orow = og + r * 8;
      float4 v = *(float4*)(smem + orow * 528 + seg * 16);
      *(float4*)(outb + (size_t)(o0 + orow) * ldo + p0 + seg * 4) = v;
    }
  } else {                        // pm bf16 via LDS bounce [128][72] halves
    ushort* El = (ushort*)smem;
    #pragma unroll
    for (int fm = 0; fm < 2; ++fm)
      #pragma unroll
      for (int fn = 0; fn < 4; ++fn)
        #pragma unroll
        for (int r = 0; r < 4; ++r) {
          const int p = wv * 32 + fm * 16 + g4 * 4 + r;
          float v = acc[fm][fn][r] + bvv[fn];
          if (RELU) v = fmaxf(v, 0.f);
          El[p * 72 + fn * 16 + lr] = f2bf(v);
        }
    __syncthreads();
    ushort* outb = (ushort*)out + (size_t)b * obstride;
    const int rg = tid >> 3, seg = tid & 7;
    #pragma unroll
    for (int r = 0; r < 4; ++r) {
      const int row = rg + r * 32;
      uint4 v = *(uint4*)(smem + row * 144 + seg * 16);
      *(uint4*)(outb + (size_t)(p0 + row) * ldo + o0 + seg * 8) = v;
    }
  }
}

// --------------------------------------------------------------------------
// gemm3_dual_k: x1 & value GEMMs in one launch (barrier-free direct-load).
// blockIdx.y<4 -> problem A, else problem B. pm bf16 out.
// --------------------------------------------------------------------------
__global__ __launch_bounds__(256) void gemm3_dual_k(
    const ushort* __restrict__ inA, const ushort* __restrict__ inB,
    const ushort* __restrict__ WbA, const ushort* __restrict__ WbB,
    const float* __restrict__ biasA, const float* __restrict__ biasB,
    ushort* __restrict__ outA, ushort* __restrict__ outB)
{
  __shared__ __align__(16) char smem[18432];
  const int tid = threadIdx.x;
  const int b = blockIdx.z;
  const int p0 = blockIdx.x * 128;
  const bool second = blockIdx.y >= 4;
  const int o0 = (blockIdx.y & 3) * 64;
  const ushort* in = second ? inB : inA;
  const ushort* Wb = second ? WbB : WbA;
  const float* bias = second ? biasB : biasA;
  ushort* out = second ? outB : outA;

  const int l = tid & 63, wv = tid >> 6;
  const int lr = l & 15, g4 = l >> 4;

  const ushort* arow = in + (size_t)b * PIX * CH + (size_t)(p0 + wv * 32 + lr) * CH + g4 * 8;
  const ushort* wrow = Wb + (size_t)(o0 + lr) * CH + g4 * 8;

  f32x4 acc[2][4];
  #pragma unroll
  for (int i = 0; i < 2; ++i)
    #pragma unroll
    for (int j = 0; j < 4; ++j) acc[i][j] = (f32x4){0.f, 0.f, 0.f, 0.f};

  #pragma unroll
  for (int t = 0; t < 8; ++t) {
    bf16x8 af[2], bfr[4];
    #pragma unroll
    for (int fm = 0; fm < 2; ++fm)
      af[fm] = *(const bf16x8*)(arow + (size_t)fm * 16 * CH + t * 32);
    #pragma unroll
    for (int fn = 0; fn < 4; ++fn)
      bfr[fn] = *(const bf16x8*)(wrow + (size_t)fn * 16 * CH + t * 32);
    #pragma unroll
    for (int fm = 0; fm < 2; ++fm)
      #pragma unroll
      for (int fn = 0; fn < 4; ++fn)
        acc[fm][fn] = __builtin_amdgcn_mfma_f32_16x16x32_bf16(af[fm], bfr[fn], acc[fm][fn], 0, 0, 0);
  }

  float bvv[4];
  #pragma unroll
  for (int fn = 0; fn < 4; ++fn) bvv[fn] = bias[o0 + fn * 16 + lr];

  ushort* El = (ushort*)smem;     // [128][72] halves
  #pragma unroll
  for (int fm = 0; fm < 2; ++fm)
    #pragma unroll
    for (int fn = 0; fn < 4; ++fn)
      #pragma unroll
      for (int r = 0; r < 4; ++r) {
        const int p = wv * 32 + fm * 16 + g4 * 4 + r;
        El[p * 72 + fn * 16 + lr] = f2bf(acc[fm][fn][r] + bvv[fn]);
      }
  __syncthreads();
  ushort* outb = out + (size_t)b * PIX * CH;
  const int rg = tid >> 3, seg = tid & 7;
  #pragma unroll
  for (int r = 0; r < 4; ++r) {
    const int row = rg + r * 32;
    uint4 v = *(uint4*)(smem + row * 144 + seg * 16);
    *(uint4*)(outb + (size_t)(p0 + row) * CH + o0 + seg * 8) = v;
  }
}

// --------------------------------------------------------------------------
// Fused MSDA — r12 verbatim (frozen local optimum).
// --------------------------------------------------------------------------
__global__ __launch_bounds__(256) void msda_k(
    const ushort* __restrict__ value, const ushort* __restrict__ sa,
    ushort* __restrict__ out)
{
  const int t = blockIdx.x * 256 + threadIdx.x;   // B*P*16
  const int dh = t & 1;
  const int h = (t >> 1) & 7;
  const int pg = t >> 4;
  const int b = pg >> 14;
  const int p = pg & (PIX - 1);
  const int px = p & 127, py = p >> 7;

  const ushort* vb = value + (size_t)b * PIX * CH;
  const ushort* sp = sa + (size_t)pg * 192;

  uint4 lgv = *(const uint4*)(sp + 128 + h * 8);
  const unsigned* lgw = (const unsigned*)&lgv;
  float lg[8];
  #pragma unroll
  for (int i = 0; i < 4; ++i) { lg[2 * i] = bfl(lgw[i]); lg[2 * i + 1] = bfh(lgw[i]); }
  float m = lg[0];
  #pragma unroll
  for (int i = 1; i < 8; ++i) m = fmaxf(m, lg[i]);
  float s = 0.f;
  #pragma unroll
  for (int i = 0; i < 8; ++i) { lg[i] = __expf(lg[i] - m); s += lg[i]; }
  const float inv = 1.f / s;

  uint4 ov0 = *(const uint4*)(sp + h * 16);
  uint4 ov1 = *(const uint4*)(sp + h * 16 + 8);
  float of[16];
  {
    const unsigned* ow = (const unsigned*)&ov0;
    #pragma unroll
    for (int i = 0; i < 4; ++i) { of[2 * i] = bfl(ow[i]); of[2 * i + 1] = bfh(ow[i]); }
    const unsigned* ow1 = (const unsigned*)&ov1;
    #pragma unroll
    for (int i = 0; i < 4; ++i) { of[8 + 2 * i] = bfl(ow1[i]); of[8 + 2 * i + 1] = bfh(ow1[i]); }
  }

  float acc[16];
  #pragma unroll
  for (int i = 0; i < 16; ++i) acc[i] = 0.f;

  #pragma unroll
  for (int pt = 0; pt < 8; ++pt) {
    const float ox = of[2 * pt], oy = of[2 * pt + 1];
    const float aw = lg[pt] * inv;
    const float ix = px + ox, iy = py + oy;   // grid_sample -0.5 cancels
    const float xf = floorf(ix), yf = floorf(iy);
    const float fx = ix - xf, fy = iy - yf;
    const int x0 = (int)xf, y0 = (int)yf;
    #pragma unroll
    for (int cr = 0; cr < 4; ++cr) {
      const int dx = cr & 1, dy = cr >> 1;
      const int xx = x0 + dx, yy = y0 + dy;
      const float wx = dx ? fx : (1.f - fx);
      const float wy = dy ? fy : (1.f - fy);
      const bool valid = ((unsigned)xx < 128u) & ((unsigned)yy < 128u);
      float w = valid ? (wx * wy * aw) : 0.f;
      const int xc = min(max(xx, 0), 127), yc = min(max(yy, 0), 127);
      const ushort* vr = vb + ((size_t)(yc * 128 + xc) * CH + h * 32 + dh * 16);
      uint4 q0 = *(const uint4*)vr;
      uint4 q1 = *(const uint4*)(vr + 8);
      const unsigned* qw0 = (const unsigned*)&q0;
      const unsigned* qw1 = (const unsigned*)&q1;
      #pragma unroll
      for (int ww = 0; ww < 4; ++ww) {
        acc[2 * ww + 0] = fmaf(w, bfl(qw0[ww]), acc[2 * ww + 0]);
        acc[2 * ww + 1] = fmaf(w, bfh(qw0[ww]), acc[2 * ww + 1]);
        acc[8 + 2 * ww + 0] = fmaf(w, bfl(qw1[ww]), acc[8 + 2 * ww + 0]);
        acc[8 + 2 * ww + 1] = fmaf(w, bfh(qw1[ww]), acc[8 + 2 * ww + 1]);
      }
    }
  }
  unsigned r[8];
  #pragma unroll
  for (int k = 0; k < 8; ++k)
    r[k] = (unsigned)f2bf(acc[2 * k]) | ((unsigned)f2bf(acc[2 * k + 1]) << 16);
  ushort* dst = out + (size_t)pg * CH + h * 32 + dh * 16;
  *(uint4*)dst = *(uint4*)&r[0];
  *(uint4*)(dst + 8) = *(uint4*)&r[4];
}

extern "C" void kernel_launch(void* const* d_in, const int* in_sizes, int n_in,
                              void* d_out, int out_size, void* d_ws, size_t ws_size,
                              hipStream_t stream)
{
  const float* xt     = (const float*)d_in[0];
  const float* xt_1   = (const float*)d_in[1];
  const float* W_in1  = (const float*)d_in[2];
  const float* b_in1  = (const float*)d_in[3];
  const float* W_in2  = (const float*)d_in[4];
  const float* b_in2  = (const float*)d_in[5];
  const float* Wv     = (const float*)d_in[6];
  const float* bv     = (const float*)d_in[7];
  const float* Ws     = (const float*)d_in[8];
  const float* bs_off = (const float*)d_in[9];
  const float* Wa     = (const float*)d_in[10];
  const float* ba     = (const float*)d_in[11];
  const float* Wo     = (const float*)d_in[12];
  const float* bo     = (const float*)d_in[13];
  const float* Wt1    = (const float*)d_in[14];
  const float* bt1    = (const float*)d_in[15];
  const float* Wt2    = (const float*)d_in[16];
  const float* bt2    = (const float*)d_in[17];
  const float* Wout   = (const float*)d_in[18];
  const float* bout   = (const float*)d_in[19];

  char* ws = (char*)d_ws;
  const size_t SLOT = (size_t)BATCH * PIX * CH * 2;          // 16.78 MB
  const size_t SAB  = (size_t)BATCH * PIX * 192 * 2;         // 12.6 MB (bf16)
  ushort* s0 = (ushort*)(ws + 0 * SLOT);   // xt_pm  -> xt_star
  ushort* s1 = (ushort*)(ws + 1 * SLOT);   // xt1_pm -> h1
  ushort* s2 = (ushort*)(ws + 2 * SLOT);   // x1 (live to end)
  ushort* s3 = (ushort*)(ws + 3 * SLOT);   // value  -> tg
  ushort* s4 = (ushort*)(ws + 4 * SLOT);   // msda_out
  ushort* sa = (ushort*)(ws + 5 * SLOT);   // [B][P][192] offs+attn (bf16)
  char* wbase = ws + 5 * SLOT + SAB;
  ushort* wb  = (ushort*)wbase;            // 1472x256 bf16
  ushort* wvp = (ushort*)(wbase + (size_t)1472 * 256 * 2);   // 256x256 bf16
  float* bsa  = (float*)(wbase + (size_t)1472 * 256 * 2 + (size_t)256 * 256 * 2);
  float* bvp  = bsa + 192;

  ushort* wb_in1 = wb;
  ushort* wb_o   = wb + 65536;
  ushort* wb_t1  = wb + 131072;
  ushort* wb_t2  = wb + 196608;
  ushort* wb_out = wb + 262144;
  ushort* wb_sa  = wb + 327680;            // 192 rows: Ws then Wa

  dim3 blk(256);
  dim3 gD(PIX / 128, 8, BATCH);            // dual x1+value
  dim3 gF(PIX / 128, 4, BATCH);            // Cout=256
  dim3 gS(PIX / 128, 3, BATCH);            // Cout=192
  const size_t OBS = (size_t)PIX * CH;     // pm bf16 batch stride (elems)

  prep_k<<<18113, blk, 0, stream>>>(xt, xt_1, s0, s1,
      W_in1, Wo, Wt1, Wt2, Wout, Ws, Wa, bs_off, ba, wb, bsa,
      Wv, W_in2, b_in2, bv, wvp, bvp);

  gemm3_dual_k<<<gD, blk, 0, stream>>>(s0, s1, wb_in1, wvp, b_in1, bvp, s2, s3); // x1 + value
  gemm3_k<0, false, 0><<<gS, blk, 0, stream>>>(s2, nullptr, wb_sa, bsa, sa, 192, (size_t)PIX * 192); // offs+attn
  msda_k<<<dim3((BATCH * PIX * 16) / 256), blk, 0, stream>>>(s3, sa, s4);
  gemm3_k<0, false, 0><<<gF, blk, 0, stream>>>(s4, nullptr, wb_o, bo, s0, CH, OBS);               // xt_star
  gemm3_k<1, true , 0><<<gF, blk, 0, stream>>>(s0, s2, wb_t1, bt1, s1, CH, OBS);                  // h1
  gemm3_k<0, false, 0><<<gF, blk, 0, stream>>>(s1, nullptr, wb_t2, bt2, s3, CH, OBS);             // tg
  gemm3_k<2, true , 1><<<gF, blk, 0, stream>>>(s3, s2, wb_out, bout, d_out, PIX, (size_t)CH * PIX); // out
}

// Round 15
// 153.204 us; speedup vs baseline: 1.6592x; 1.6592x over previous
//
#include <hip/hip_runtime.h>
#include <math.h>

// ---------------------------------------------------------------------------
// TemporalGuidedModule round 15 = r12 (155us best) + counted-vmcnt pipelined
// staging (T3/T4) for FUSE=0 GEMMs:
//  gemm2p_k / gemm2p_dual_k: 3-buffer LDS (36KB), raw s_barrier + asm
//  s_waitcnt vmcnt(3) -> tile t+2 loads stay in flight across barriers
//  (r12's __syncthreads forced vmcnt(0) drain = the ~20% stall, m97).
//  FUSE kernels (h1, out) keep the r12 gemm2_k path verbatim.
//  r14's direct-load experiment reverted (staging = coalescing transform).
// ---------------------------------------------------------------------------

#define PIX 16384
#define BATCH 2
#define CH 256

typedef short bf16x8 __attribute__((ext_vector_type(8)));
typedef float f32x4 __attribute__((ext_vector_type(4)));

typedef const __attribute__((address_space(1))) void* as1cv;
typedef __attribute__((address_space(3))) void* as3v;
__device__ __forceinline__ void gl_lds16(const void* g, void* l) {
  __builtin_amdgcn_global_load_lds((as1cv)g, (as3v)l, 16, 0, 0);
}

__device__ __forceinline__ ushort f2bf(float f) {
  union { float f; unsigned u; } v; v.f = f;
  unsigned u = v.u;
  unsigned r = u + 0x7fffu + ((u >> 16) & 1u);   // RNE
  return (ushort)(r >> 16);
}
__device__ __forceinline__ float bfl(unsigned u) {
  union { unsigned u; float f; } v; v.u = u << 16; return v.f;
}
__device__ __forceinline__ float bfh(unsigned u) {
  union { unsigned u; float f; } v; v.u = u & 0xffff0000u; return v.f;
}
__device__ __forceinline__ unsigned fuse_u32(unsigned a, unsigned b, bool mul) {
  float rl = mul ? bfl(a) * bfl(b) : bfl(a) + bfl(b);
  float rh = mul ? bfh(a) * bfh(b) : bfh(a) + bfh(b);
  return (unsigned)f2bf(rl) | ((unsigned)f2bf(rh) << 16);
}

// --------------------------------------------------------------------------
// prep_k: merged tconv(x2 tensors) + weight-prep + Wv-composite (r12 verbatim).
// --------------------------------------------------------------------------
__global__ __launch_bounds__(256) void prep_k(
    const float* __restrict__ xt, const float* __restrict__ xt_1,
    ushort* __restrict__ s0, ushort* __restrict__ s1,
    const float* __restrict__ W_in1, const float* __restrict__ Wo,
    const float* __restrict__ Wt1, const float* __restrict__ Wt2,
    const float* __restrict__ Wout, const float* __restrict__ Ws,
    const float* __restrict__ Wa, const float* __restrict__ bs_off,
    const float* __restrict__ ba, ushort* __restrict__ wb,
    float* __restrict__ bsa,
    const float* __restrict__ Wv, const float* __restrict__ W_in2,
    const float* __restrict__ b_in2, const float* __restrict__ bv,
    ushort* __restrict__ wvp, float* __restrict__ bvp)
{
  __shared__ float lds[32][33];
  const int bid = blockIdx.x;
  const int tid = threadIdx.x;

  if (bid < 16384) {
    const int z = bid >> 12;
    const int rem = bid & 4095;
    const int pblk = rem & 511, cblk = rem >> 9;
    const int b = z & 1;
    const float* in = (z < 2) ? xt : xt_1;
    ushort* out = (z < 2) ? s0 : s1;
    const int p0 = pblk * 32, c0 = cblk * 32;
    const int tx = tid & 31, ty = tid >> 5;
    const float* inb = in + (size_t)b * CH * PIX;
    #pragma unroll
    for (int i = 0; i < 4; ++i)
      lds[ty + i * 8][tx] = inb[(size_t)(c0 + ty + i * 8) * PIX + p0 + tx];
    __syncthreads();
    const int cx = (tid & 15) * 2, py = tid >> 4;
    ushort* outb = out + (size_t)b * PIX * CH;
    #pragma unroll
    for (int i = 0; i < 2; ++i) {
      int pl = py + i * 16;
      unsigned lo = f2bf(lds[cx][pl]);
      unsigned hi = f2bf(lds[cx + 1][pl]);
      *(unsigned*)(outb + (size_t)(p0 + pl) * CH + c0 + cx) = lo | (hi << 16);
    }
  } else if (bid < 16384 + 1473) {
    const int blk = bid - 16384;
    const int k = tid;
    if (blk >= 1472) {
      if (k < 128) bsa[k] = bs_off[k];
      else if (k < 192) bsa[k] = ba[k - 128];
      return;
    }
    const float* src;
    if (blk < 256) src = W_in1 + (size_t)blk * 256;
    else if (blk < 512) src = Wo + (size_t)(blk - 256) * 256;
    else if (blk < 768) src = Wt1 + (size_t)(blk - 512) * 256;
    else if (blk < 1024) src = Wt2 + (size_t)(blk - 768) * 256;
    else if (blk < 1280) src = Wout + (size_t)(blk - 1024) * 256;
    else if (blk < 1408) src = Ws + (size_t)(blk - 1280) * 256;
    else src = Wa + (size_t)(blk - 1408) * 256;
    wb[(size_t)blk * 256 + k] = f2bf(src[k]);
  } else {
    const int oo = bid - 17857;
    const int k = tid;
    float acc = 0.f;
    #pragma unroll 8
    for (int c = 0; c < 256; ++c)
      acc += Wv[(size_t)oo * 256 + c] * W_in2[(size_t)c * 256 + k];
    wvp[(size_t)oo * 256 + k] = f2bf(acc);
    float* red = &lds[0][0];
    red[k] = Wv[(size_t)oo * 256 + k] * b_in2[k];
    __syncthreads();
    for (int s = 128; s > 0; s >>= 1) {
      if (k < s) red[k] += red[k + s];
      __syncthreads();
    }
    if (k == 0) bvp[oo] = red[0] + bv[oo];
  }
}

// --------------------------------------------------------------------------
// gemm2p_k: FUSE=0 pipelined GEMM. 128p x 64o, BK=32, 8 K-steps, 4 waves.
// 3-buffer LDS (X: 3x8KB @0, W: 3x4KB @24576 = 36KB). Counted vmcnt:
// stage tile t+2 during t; end-of-iter waits vmcnt(3) (tile t+1 landed,
// t+2 still in flight) + raw s_barrier. gl_lds dest lane-linear, source
// pre-swizzled (r10 involution). Epilogue identical to r12.
// OMODE 0: pm bf16 out (ldo).
// --------------------------------------------------------------------------
template<bool RELU, int OMODE>
__global__ __launch_bounds__(256, 4) void gemm2p_k(
    const ushort* __restrict__ in, const ushort* __restrict__ Wb,
    const float* __restrict__ bias, void* __restrict__ out,
    int ldo, size_t obstride)
{
  __shared__ __align__(16) char smem[36864];
  const int tid = threadIdx.x;
  const int b = blockIdx.z;
  const int p0 = blockIdx.x * 128;
  const int o0 = blockIdx.y * 64;

  const ushort* inb = in + (size_t)b * PIX * CH;

  const int srow = tid >> 2;
  const int sseg = tid & 3;
  const int swz0 = (srow >> 1) & 3;
  const int swz1 = ((srow + 64) >> 1) & 3;
  const int gseg0 = sseg ^ swz0;
  const int gseg1 = sseg ^ swz1;
  const ushort* xsrc0 = inb + (size_t)(p0 + srow) * CH + gseg0 * 8;
  const ushort* xsrc1 = inb + (size_t)(p0 + srow + 64) * CH + gseg1 * 8;
  const ushort* wsrc = Wb + (size_t)(o0 + srow) * CH + gseg0 * 8;

  const int l = tid & 63, wv = tid >> 6;
  const int lr = l & 15, g4 = l >> 4;

  f32x4 acc[2][4];
  #pragma unroll
  for (int i = 0; i < 2; ++i)
    #pragma unroll
    for (int j = 0; j < 4; ++j) acc[i][j] = (f32x4){0.f, 0.f, 0.f, 0.f};

#define STAGE_P(buf, kb)                                                       \
  {                                                                            \
    gl_lds16(xsrc0 + (kb), smem + (buf) * 8192 + tid * 16);                    \
    gl_lds16(xsrc1 + (kb), smem + (buf) * 8192 + 4096 + tid * 16);             \
    gl_lds16(wsrc + (kb), smem + 24576 + (buf) * 4096 + tid * 16);             \
  }

  STAGE_P(0, 0)
  STAGE_P(1, 32)
  asm volatile("s_waitcnt vmcnt(3)" ::: "memory");   // tile 0 landed
  __builtin_amdgcn_s_barrier();

  for (int t = 0; t < 8; ++t) {
    if (t < 6) STAGE_P((t + 2) % 3, (t + 2) * 32)
    const char* XB = smem + (t % 3) * 8192;
    const char* WB = smem + 24576 + (t % 3) * 4096;
    bf16x8 af[2], bfr[4];
    #pragma unroll
    for (int fm = 0; fm < 2; ++fm) {
      const int p = wv * 32 + fm * 16 + lr;
      af[fm] = *(const bf16x8*)(XB + p * 64 + ((g4 ^ ((p >> 1) & 3)) * 16));
    }
    #pragma unroll
    for (int fn = 0; fn < 4; ++fn) {
      const int o = fn * 16 + lr;
      bfr[fn] = *(const bf16x8*)(WB + o * 64 + ((g4 ^ ((o >> 1) & 3)) * 16));
    }
    #pragma unroll
    for (int fm = 0; fm < 2; ++fm)
      #pragma unroll
      for (int fn = 0; fn < 4; ++fn)
        acc[fm][fn] = __builtin_amdgcn_mfma_f32_16x16x32_bf16(af[fm], bfr[fn], acc[fm][fn], 0, 0, 0);
    if (t < 7) {
      if (t < 6) asm volatile("s_waitcnt vmcnt(3)" ::: "memory");  // t+1 landed
      else       asm volatile("s_waitcnt vmcnt(0)" ::: "memory");  // t+1 (last) landed
      __builtin_amdgcn_s_barrier();
    }
  }
#undef STAGE_P
  // all ds_reads consumed by MFMAs above; barrier before LDS reuse in epilogue
  __builtin_amdgcn_s_barrier();

  float bvv[4];
  #pragma unroll
  for (int fn = 0; fn < 4; ++fn) bvv[fn] = bias[o0 + fn * 16 + lr];

  ushort* El = (ushort*)smem;     // [128][72] halves
  #pragma unroll
  for (int fm = 0; fm < 2; ++fm)
    #pragma unroll
    for (int fn = 0; fn < 4; ++fn)
      #pragma unroll
      for (int r = 0; r < 4; ++r) {
        const int p = wv * 32 + fm * 16 + g4 * 4 + r;
        float v = acc[fm][fn][r] + bvv[fn];
        if (RELU) v = fmaxf(v, 0.f);
        El[p * 72 + fn * 16 + lr] = f2bf(v);
      }
  __syncthreads();
  ushort* outb = (ushort*)out + (size_t)b * obstride;
  const int rg = tid >> 3, seg = tid & 7;
  #pragma unroll
  for (int r = 0; r < 4; ++r) {
    const int row = rg + r * 32;
    uint4 v = *(uint4*)(smem + row * 144 + seg * 16);
    *(uint4*)(outb + (size_t)(p0 + row) * ldo + o0 + seg * 8) = v;
  }
}

// --------------------------------------------------------------------------
// gemm2p_dual_k: x1 & value GEMMs in one pipelined launch (blockIdx.y<4 -> A).
// --------------------------------------------------------------------------
__global__ __launch_bounds__(256, 4) void gemm2p_dual_k(
    const ushort* __restrict__ inA, const ushort* __restrict__ inB,
    const ushort* __restrict__ WbA, const ushort* __restrict__ WbB,
    const float* __restrict__ biasA, const float* __restrict__ biasB,
    ushort* __restrict__ outA, ushort* __restrict__ outB)
{
  __shared__ __align__(16) char smem[36864];
  const int tid = threadIdx.x;
  const int b = blockIdx.z;
  const int p0 = blockIdx.x * 128;
  const bool second = blockIdx.y >= 4;
  const int o0 = (blockIdx.y & 3) * 64;
  const ushort* in = second ? inB : inA;
  const ushort* Wb = second ? WbB : WbA;
  const float* bias = second ? biasB : biasA;
  ushort* out = second ? outB : outA;

  const ushort* inb = in + (size_t)b * PIX * CH;

  const int srow = tid >> 2;
  const int sseg = tid & 3;
  const int swz0 = (srow >> 1) & 3;
  const int swz1 = ((srow + 64) >> 1) & 3;
  const int gseg0 = sseg ^ swz0;
  const int gseg1 = sseg ^ swz1;
  const ushort* xsrc0 = inb + (size_t)(p0 + srow) * CH + gseg0 * 8;
  const ushort* xsrc1 = inb + (size_t)(p0 + srow + 64) * CH + gseg1 * 8;
  const ushort* wsrc = Wb + (size_t)(o0 + srow) * CH + gseg0 * 8;

  const int l = tid & 63, wv = tid >> 6;
  const int lr = l & 15, g4 = l >> 4;

  f32x4 acc[2][4];
  #pragma unroll
  for (int i = 0; i < 2; ++i)
    #pragma unroll
    for (int j = 0; j < 4; ++j) acc[i][j] = (f32x4){0.f, 0.f, 0.f, 0.f};

#define STAGE_P(buf, kb)                                                       \
  {                                                                            \
    gl_lds16(xsrc0 + (kb), smem + (buf) * 8192 + tid * 16);                    \
    gl_lds16(xsrc1 + (kb), smem + (buf) * 8192 + 4096 + tid * 16);             \
    gl_lds16(wsrc + (kb), smem + 24576 + (buf) * 4096 + tid * 16);             \
  }

  STAGE_P(0, 0)
  STAGE_P(1, 32)
  asm volatile("s_waitcnt vmcnt(3)" ::: "memory");
  __builtin_amdgcn_s_barrier();

  for (int t = 0; t < 8; ++t) {
    if (t < 6) STAGE_P((t + 2) % 3, (t + 2) * 32)
    const char* XB = smem + (t % 3) * 8192;
    const char* WB = smem + 24576 + (t % 3) * 4096;
    bf16x8 af[2], bfr[4];
    #pragma unroll
    for (int fm = 0; fm < 2; ++fm) {
      const int p = wv * 32 + fm * 16 + lr;
      af[fm] = *(const bf16x8*)(XB + p * 64 + ((g4 ^ ((p >> 1) & 3)) * 16));
    }
    #pragma unroll
    for (int fn = 0; fn < 4; ++fn) {
      const int o = fn * 16 + lr;
      bfr[fn] = *(const bf16x8*)(WB + o * 64 + ((g4 ^ ((o >> 1) & 3)) * 16));
    }
    #pragma unroll
    for (int fm = 0; fm < 2; ++fm)
      #pragma unroll
      for (int fn = 0; fn < 4; ++fn)
        acc[fm][fn] = __builtin_amdgcn_mfma_f32_16x16x32_bf16(af[fm], bfr[fn], acc[fm][fn], 0, 0, 0);
    if (t < 7) {
      if (t < 6) asm volatile("s_waitcnt vmcnt(3)" ::: "memory");
      else       asm volatile("s_waitcnt vmcnt(0)" ::: "memory");
      __builtin_amdgcn_s_barrier();
    }
  }
#undef STAGE_P
  __builtin_amdgcn_s_barrier();

  float bvv[4];
  #pragma unroll
  for (int fn = 0; fn < 4; ++fn) bvv[fn] = bias[o0 + fn * 16 + lr];

  ushort* El = (ushort*)smem;     // [128][72] halves
  #pragma unroll
  for (int fm = 0; fm < 2; ++fm)
    #pragma unroll
    for (int fn = 0; fn < 4; ++fn)
      #pragma unroll
      for (int r = 0; r < 4; ++r) {
        const int p = wv * 32 + fm * 16 + g4 * 4 + r;
        El[p * 72 + fn * 16 + lr] = f2bf(acc[fm][fn][r] + bvv[fn]);
      }
  __syncthreads();
  ushort* outb = out + (size_t)b * PIX * CH;
  const int rg = tid >> 3, seg = tid & 7;
  #pragma unroll
  for (int r = 0; r < 4; ++r) {
    const int row = rg + r * 32;
    uint4 v = *(uint4*)(smem + row * 144 + seg * 16);
    *(uint4*)(outb + (size_t)(p0 + row) * CH + o0 + seg * 8) = v;
  }
}

// --------------------------------------------------------------------------
// gemm2_k (r12 verbatim): used for the FUSE!=0 GEMMs (h1, out).
// --------------------------------------------------------------------------
template<int FUSE, bool RELU, int OMODE>
__global__ __launch_bounds__(256, 4) void gemm2_k(
    const ushort* __restrict__ in, const ushort* __restrict__ in2,
    const ushort* __restrict__ Wb, const float* __restrict__ bias,
    void* __restrict__ out, int ldo, size_t obstride)
{
  constexpr int SMEMSZ = (OMODE == 0) ? 24576 : 34816;
  __shared__ __align__(16) char smem[SMEMSZ];
  const int tid = threadIdx.x;
  const int b = blockIdx.z;
  const int p0 = blockIdx.x * 128;
  const int o0 = blockIdx.y * 64;

  const ushort* inb = in + (size_t)b * PIX * CH;

  const int srow = tid >> 2;
  const int sseg = tid & 3;
  const int swz0 = (srow >> 1) & 3;
  const int swz1 = ((srow + 64) >> 1) & 3;
  const ushort* xsrc0 = inb + (size_t)(p0 + srow) * CH + sseg * 8;
  const ushort* xsrc1 = inb + (size_t)(p0 + srow + 64) * CH + sseg * 8;
  const ushort* x2src0 = in2 + (size_t)b * PIX * CH + (size_t)(p0 + srow) * CH + sseg * 8;
  const ushort* x2src1 = in2 + (size_t)b * PIX * CH + (size_t)(p0 + srow + 64) * CH + sseg * 8;
  const ushort* wsrc = Wb + (size_t)(o0 + srow) * CH + (sseg ^ swz0) * 8;

  const int l = tid & 63, wv = tid >> 6;
  const int lr = l & 15, g4 = l >> 4;

  f32x4 acc[2][4];
  #pragma unroll
  for (int i = 0; i < 2; ++i)
    #pragma unroll
    for (int j = 0; j < 4; ++j) acc[i][j] = (f32x4){0.f, 0.f, 0.f, 0.f};

  uint4 xr[2], x2r[2], wr;

#define LOADT(kb)                                                              \
  {                                                                            \
    xr[0] = *(const uint4*)(xsrc0 + (kb));                                     \
    xr[1] = *(const uint4*)(xsrc1 + (kb));                                     \
    x2r[0] = *(const uint4*)(x2src0 + (kb));                                   \
    x2r[1] = *(const uint4*)(x2src1 + (kb));                                   \
    wr = *(const uint4*)(wsrc + (kb));                                         \
  }

#define WRITET(buf)                                                            \
  {                                                                            \
    _Pragma("unroll")                                                          \
    for (int r = 0; r < 2; ++r) {                                              \
      uint4 v = xr[r];                                                         \
      unsigned* pa = (unsigned*)&v;                                            \
      const unsigned* pb = (const unsigned*)&x2r[r];                           \
      _Pragma("unroll")                                                        \
      for (int w = 0; w < 4; ++w) pa[w] = fuse_u32(pa[w], pb[w], FUSE == 1);   \
      const int sw = r ? swz1 : swz0;                                          \
      *(uint4*)(smem + (buf) * 8192 + r * 4096 + srow * 64 +                   \
                ((sseg ^ sw) * 16)) = v;                                       \
    }                                                                          \
    gl_lds16(wsrc + (buf##_kb), smem + 16384 + (buf) * 4096 + tid * 16);       \
  }

  // NOTE: W staged via gl_lds (pre-swizzled source); X via register fuse path.
  int b0_kb, b1_kb; (void)b0_kb; (void)b1_kb;
  LOADT(0)
  b0_kb = 0;
  {
    _Pragma("unroll")
    for (int r = 0; r < 2; ++r) {
      uint4 v = xr[r];
      unsigned* pa = (unsigned*)&v;
      const unsigned* pb = (const unsigned*)&x2r[r];
      _Pragma("unroll")
      for (int w = 0; w < 4; ++w) pa[w] = fuse_u32(pa[w], pb[w], FUSE == 1);
      const int sw = r ? swz1 : swz0;
      *(uint4*)(smem + r * 4096 + srow * 64 + ((sseg ^ sw) * 16)) = v;
    }
    gl_lds16(wsrc + 0, smem + 16384 + tid * 16);
  }
  __syncthreads();

  for (int t = 0; t < 8; ++t) {
    if (t < 7) {
      LOADT((t + 1) * 32)
    }
    const char* XB = smem + (t & 1) * 8192;
    const char* WB = smem + 16384 + (t & 1) * 4096;
    bf16x8 af[2], bfr[4];
    #pragma unroll
    for (int fm = 0; fm < 2; ++fm) {
      const int p = wv * 32 + fm * 16 + lr;
      af[fm] = *(const bf16x8*)(XB + p * 64 + ((g4 ^ ((p >> 1) & 3)) * 16));
    }
    #pragma unroll
    for (int fn = 0; fn < 4; ++fn) {
      const int o = fn * 16 + lr;
      bfr[fn] = *(const bf16x8*)(WB + o * 64 + ((g4 ^ ((o >> 1) & 3)) * 16));
    }
    #pragma unroll
    for (int fm = 0; fm < 2; ++fm)
      #pragma unroll
      for (int fn = 0; fn < 4; ++fn)
        acc[fm][fn] = __builtin_amdgcn_mfma_f32_16x16x32_bf16(af[fm], bfr[fn], acc[fm][fn], 0, 0, 0);
    if (t < 7) {
      const int buf = (t + 1) & 1;
      _Pragma("unroll")
      for (int r = 0; r < 2; ++r) {
        uint4 v = xr[r];
        unsigned* pa = (unsigned*)&v;
        const unsigned* pb = (const unsigned*)&x2r[r];
        _Pragma("unroll")
        for (int w = 0; w < 4; ++w) pa[w] = fuse_u32(pa[w], pb[w], FUSE == 1);
        const int sw = r ? swz1 : swz0;
        *(uint4*)(smem + buf * 8192 + r * 4096 + srow * 64 + ((sseg ^ sw) * 16)) = v;
      }
      gl_lds16(wsrc + (t + 1) * 32, smem + 16384 + buf * 4096 + tid * 16);
    }
    __syncthreads();
  }
#undef LOADT
#undef WRITET

  float bvv[4];
  #pragma unroll
  for (int fn = 0; fn < 4; ++fn) bvv[fn] = bias[o0 + fn * 16 + lr];

  if (OMODE == 1) {               // cm f32 via TRANSPOSED bounce El2[64][132] f32
    float* El2 = (float*)smem;
    #pragma unroll
    for (int fm = 0; fm < 2; ++fm)
      #pragma unroll
      for (int fn = 0; fn < 4; ++fn) {
        float4 v;
        v.x = acc[fm][fn][0] + bvv[fn]; v.y = acc[fm][fn][1] + bvv[fn];
        v.z = acc[fm][fn][2] + bvv[fn]; v.w = acc[fm][fn][3] + bvv[fn];
        if (RELU) {
          v.x = fmaxf(v.x, 0.f); v.y = fmaxf(v.y, 0.f);
          v.z = fmaxf(v.z, 0.f); v.w = fmaxf(v.w, 0.f);
        }
        *(float4*)&El2[(size_t)(fn * 16 + lr) * 132 + wv * 32 + fm * 16 + g4 * 4] = v;
      }
    __syncthreads();
    float* outb = (float*)out + (size_t)b * obstride;
    const int og = tid >> 5, seg = tid & 31;
    #pragma unroll
    for (int r = 0; r < 8; ++r) {
      const int orow = og + r * 8;
      float4 v = *(float4*)(smem + orow * 528 + seg * 16);
      *(float4*)(outb + (size_t)(o0 + orow) * ldo + p0 + seg * 4) = v;
    }
  } else {                        // pm bf16 via LDS bounce [128][72] halves
    ushort* El = (ushort*)smem;
    #pragma unroll
    for (int fm = 0; fm < 2; ++fm)
      #pragma unroll
      for (int fn = 0; fn < 4; ++fn)
        #pragma unroll
        for (int r = 0; r < 4; ++r) {
          const int p = wv * 32 + fm * 16 + g4 * 4 + r;
          float v = acc[fm][fn][r] + bvv[fn];
          if (RELU) v = fmaxf(v, 0.f);
          El[p * 72 + fn * 16 + lr] = f2bf(v);
        }
    __syncthreads();
    ushort* outb = (ushort*)out + (size_t)b * obstride;
    const int rg = tid >> 3, seg = tid & 7;
    #pragma unroll
    for (int r = 0; r < 4; ++r) {
      const int row = rg + r * 32;
      uint4 v = *(uint4*)(smem + row * 144 + seg * 16);
      *(uint4*)(outb + (size_t)(p0 + row) * ldo + o0 + seg * 8) = v;
    }
  }
}

// --------------------------------------------------------------------------
// Fused MSDA — r12 verbatim (frozen local optimum).
// --------------------------------------------------------------------------
__global__ __launch_bounds__(256) void msda_k(
    const ushort* __restrict__ value, const ushort* __restrict__ sa,
    ushort* __restrict__ out)
{
  const int t = blockIdx.x * 256 + threadIdx.x;   // B*P*16
  const int dh = t & 1;
  const int h = (t >> 1) & 7;
  const int pg = t >> 4;
  const int b = pg >> 14;
  const int p = pg & (PIX - 1);
  const int px = p & 127, py = p >> 7;

  const ushort* vb = value + (size_t)b * PIX * CH;
  const ushort* sp = sa + (size_t)pg * 192;

  uint4 lgv = *(const uint4*)(sp + 128 + h * 8);
  const unsigned* lgw = (const unsigned*)&lgv;
  float lg[8];
  #pragma unroll
  for (int i = 0; i < 4; ++i) { lg[2 * i] = bfl(lgw[i]); lg[2 * i + 1] = bfh(lgw[i]); }
  float m = lg[0];
  #pragma unroll
  for (int i = 1; i < 8; ++i) m = fmaxf(m, lg[i]);
  float s = 0.f;
  #pragma unroll
  for (int i = 0; i < 8; ++i) { lg[i] = __expf(lg[i] - m); s += lg[i]; }
  const float inv = 1.f / s;

  uint4 ov0 = *(const uint4*)(sp + h * 16);
  uint4 ov1 = *(const uint4*)(sp + h * 16 + 8);
  float of[16];
  {
    const unsigned* ow = (const unsigned*)&ov0;
    #pragma unroll
    for (int i = 0; i < 4; ++i) { of[2 * i] = bfl(ow[i]); of[2 * i + 1] = bfh(ow[i]); }
    const unsigned* ow1 = (const unsigned*)&ov1;
    #pragma unroll
    for (int i = 0; i < 4; ++i) { of[8 + 2 * i] = bfl(ow1[i]); of[8 + 2 * i + 1] = bfh(ow1[i]); }
  }

  float acc[16];
  #pragma unroll
  for (int i = 0; i < 16; ++i) acc[i] = 0.f;

  #pragma unroll
  for (int pt = 0; pt < 8; ++pt) {
    const float ox = of[2 * pt], oy = of[2 * pt + 1];
    const float aw = lg[pt] * inv;
    const float ix = px + ox, iy = py + oy;   // grid_sample -0.5 cancels
    const float xf = floorf(ix), yf = floorf(iy);
    const float fx = ix - xf, fy = iy - yf;
    const int x0 = (int)xf, y0 = (int)yf;
    #pragma unroll
    for (int cr = 0; cr < 4; ++cr) {
      const int dx = cr & 1, dy = cr >> 1;
      const int xx = x0 + dx, yy = y0 + dy;
      const float wx = dx ? fx : (1.f - fx);
      const float wy = dy ? fy : (1.f - fy);
      const bool valid = ((unsigned)xx < 128u) & ((unsigned)yy < 128u);
      float w = valid ? (wx * wy * aw) : 0.f;
      const int xc = min(max(xx, 0), 127), yc = min(max(yy, 0), 127);
      const ushort* vr = vb + ((size_t)(yc * 128 + xc) * CH + h * 32 + dh * 16);
      uint4 q0 = *(const uint4*)vr;
      uint4 q1 = *(const uint4*)(vr + 8);
      const unsigned* qw0 = (const unsigned*)&q0;
      const unsigned* qw1 = (const unsigned*)&q1;
      #pragma unroll
      for (int ww = 0; ww < 4; ++ww) {
        acc[2 * ww + 0] = fmaf(w, bfl(qw0[ww]), acc[2 * ww + 0]);
        acc[2 * ww + 1] = fmaf(w, bfh(qw0[ww]), acc[2 * ww + 1]);
        acc[8 + 2 * ww + 0] = fmaf(w, bfl(qw1[ww]), acc[8 + 2 * ww + 0]);
        acc[8 + 2 * ww + 1] = fmaf(w, bfh(qw1[ww]), acc[8 + 2 * ww + 1]);
      }
    }
  }
  unsigned r[8];
  #pragma unroll
  for (int k = 0; k < 8; ++k)
    r[k] = (unsigned)f2bf(acc[2 * k]) | ((unsigned)f2bf(acc[2 * k + 1]) << 16);
  ushort* dst = out + (size_t)pg * CH + h * 32 + dh * 16;
  *(uint4*)dst = *(uint4*)&r[0];
  *(uint4*)(dst + 8) = *(uint4*)&r[4];
}

extern "C" void kernel_launch(void* const* d_in, const int* in_sizes, int n_in,
                              void* d_out, int out_size, void* d_ws, size_t ws_size,
                              hipStream_t stream)
{
  const float* xt     = (const float*)d_in[0];
  const float* xt_1   = (const float*)d_in[1];
  const float* W_in1  = (const float*)d_in[2];
  const float* b_in1  = (const float*)d_in[3];
  const float* W_in2  = (const float*)d_in[4];
  const float* b_in2  = (const float*)d_in[5];
  const float* Wv     = (const float*)d_in[6];
  const float* bv     = (const float*)d_in[7];
  const float* Ws     = (const float*)d_in[8];
  const float* bs_off = (const float*)d_in[9];
  const float* Wa     = (const float*)d_in[10];
  const float* ba     = (const float*)d_in[11];
  const float* Wo     = (const float*)d_in[12];
  const float* bo     = (const float*)d_in[13];
  const float* Wt1    = (const float*)d_in[14];
  const float* bt1    = (const float*)d_in[15];
  const float* Wt2    = (const float*)d_in[16];
  const float* bt2    = (const float*)d_in[17];
  const float* Wout   = (const float*)d_in[18];
  const float* bout   = (const float*)d_in[19];

  char* ws = (char*)d_ws;
  const size_t SLOT = (size_t)BATCH * PIX * CH * 2;          // 16.78 MB
  const size_t SAB  = (size_t)BATCH * PIX * 192 * 2;         // 12.6 MB (bf16)
  ushort* s0 = (ushort*)(ws + 0 * SLOT);   // xt_pm  -> xt_star
  ushort* s1 = (ushort*)(ws + 1 * SLOT);   // xt1_pm -> h1
  ushort* s2 = (ushort*)(ws + 2 * SLOT);   // x1 (live to end)
  ushort* s3 = (ushort*)(ws + 3 * SLOT);   // value  -> tg
  ushort* s4 = (ushort*)(ws + 4 * SLOT);   // msda_out
  ushort* sa = (ushort*)(ws + 5 * SLOT);   // [B][P][192] offs+attn (bf16)
  char* wbase = ws + 5 * SLOT + SAB;
  ushort* wb  = (ushort*)wbase;            // 1472x256 bf16
  ushort* wvp = (ushort*)(wbase + (size_t)1472 * 256 * 2);   // 256x256 bf16
  float* bsa  = (float*)(wbase + (size_t)1472 * 256 * 2 + (size_t)256 * 256 * 2);
  float* bvp  = bsa + 192;

  ushort* wb_in1 = wb;
  ushort* wb_o   = wb + 65536;
  ushort* wb_t1  = wb + 131072;
  ushort* wb_t2  = wb + 196608;
  ushort* wb_out = wb + 262144;
  ushort* wb_sa  = wb + 327680;            // 192 rows: Ws then Wa

  dim3 blk(256);
  dim3 gD(PIX / 128, 8, BATCH);            // dual x1+value
  dim3 gF(PIX / 128, 4, BATCH);            // Cout=256
  dim3 gS(PIX / 128, 3, BATCH);            // Cout=192
  const size_t OBS = (size_t)PIX * CH;     // pm bf16 batch stride (elems)

  prep_k<<<18113, blk, 0, stream>>>(xt, xt_1, s0, s1,
      W_in1, Wo, Wt1, Wt2, Wout, Ws, Wa, bs_off, ba, wb, bsa,
      Wv, W_in2, b_in2, bv, wvp, bvp);

  gemm2p_dual_k<<<gD, blk, 0, stream>>>(s0, s1, wb_in1, wvp, b_in1, bvp, s2, s3); // x1 + value
  gemm2p_k<false, 0><<<gS, blk, 0, stream>>>(s2, wb_sa, bsa, sa, 192, (size_t)PIX * 192); // offs+attn
  msda_k<<<dim3((BATCH * PIX * 16) / 256), blk, 0, stream>>>(s3, sa, s4);
  gemm2p_k<false, 0><<<gF, blk, 0, stream>>>(s4, wb_o, bo, s0, CH, OBS);                  // xt_star
  gemm2_k<1, true , 0><<<gF, blk, 0, stream>>>(s0, s2, wb_t1, bt1, s1, CH, OBS);          // h1
  gemm2p_k<false, 0><<<gF, blk, 0, stream>>>(s1, wb_t2, bt2, s3, CH, OBS);                // tg
  gemm2_k<2, true , 1><<<gF, blk, 0, stream>>>(s3, s2, wb_out, bout, d_out, PIX, (size_t)CH * PIX); // out
}